// Round 1
// baseline (26.386 us; speedup 1.0000x reference)
//
#include <hip/hip_runtime.h>
#include <math.h>

// MACE equivariant score head, restructured.
// Dead-code: Wss (d_in[5]) and Wvv (d_in[7]) never reach the output (s3 is deleted).
// out[n,m] = scale * sum_u vraw[n,u,m] * h[n,u]
// h[n,u]   = t[n]*b[u] + sum_q feat[n,q] * M[q,u]
// Precompute (per launch, n-independent):
//   WsvW2[u,v] = sum_w Wsv[u,v,w]*W2[w]
//   A[p,v]     = sum_u W1_s[p,u]*WsvW2[u,v]
//   M[q,u]     = scale * sum_v A[16+q,v]*W1_v[u,v]
//   b[u]       = scale * sum_v (sum_{p<16} W_t[p]*A[p,v]) * W1_v[u,v]
//   scale      = 1/(S * V * sqrt(V))   (all fan-in norms folded)

#define S 144
#define V 128
#define FSC 128
#define NROW 4096

// ---------------- K1: WsvW2[u*V+v] = dot(Wsv[u,v,:], W2) ----------------
// uv = u*V+v enumerates rows of Wsv contiguously (reduce over last dim).
__global__ __launch_bounds__(256) void k1_wsvw2(const float* __restrict__ Wsv,
                                                const float* __restrict__ W2,
                                                float* __restrict__ out) {
    const int wave = threadIdx.x >> 6;
    const int lane = threadIdx.x & 63;
    const int uv = blockIdx.x * 4 + wave;       // grid 4608 -> uv in [0,18432)
    const float2* src = (const float2*)Wsv + (size_t)uv * 64;
    const float2* w2 = (const float2*)W2;
    float2 a = src[lane];
    float2 w = w2[lane];
    float acc = a.x * w.x + a.y * w.y;
#pragma unroll
    for (int off = 1; off < 64; off <<= 1)
        acc += __shfl_xor(acc, off, 64);
    if (lane == 0) out[uv] = acc;
}

// ---------------- K2: A[p*V+v] = sum_u W1_s[p*S+u]*WsvW2[u*V+v] ----------------
__global__ __launch_bounds__(128) void k2_A(const float* __restrict__ W1s,
                                            const float* __restrict__ WsvW2,
                                            float* __restrict__ A) {
    const int p = blockIdx.x;   // 0..143
    const int v = threadIdx.x;  // 0..127
    float acc = 0.f;
#pragma unroll 8
    for (int u = 0; u < S; ++u)
        acc = fmaf(W1s[p * S + u], WsvW2[u * V + v], acc);
    A[p * V + v] = acc;
}

// ---------------- K3: M[q*V+u], b[u] ----------------
__global__ __launch_bounds__(128) void k3_Mb(const float* __restrict__ A,
                                             const float* __restrict__ W1v,
                                             const float* __restrict__ Wt,
                                             float* __restrict__ M,
                                             float* __restrict__ b) {
    const float scale = 1.0f / (144.0f * 128.0f * sqrtf(128.0f));
    __shared__ float lds_a[V];
    const int u = threadIdx.x;  // 0..127
    const int q = blockIdx.x;   // 0..128 (128 == b row)
    if (q < V) {
        const float4* a4 = (const float4*)(A + (size_t)(16 + q) * V);
        const float4* w4 = (const float4*)(W1v + (size_t)u * V);
        float acc = 0.f;
#pragma unroll
        for (int i = 0; i < V / 4; ++i) {
            float4 av = a4[i], wv = w4[i];
            acc += av.x * wv.x + av.y * wv.y + av.z * wv.z + av.w * wv.w;
        }
        M[q * V + u] = acc * scale;
    } else {
        // a[v] = sum_{p<16} Wt[p]*A[p*V+v]  (thread index doubles as v here)
        float av = 0.f;
#pragma unroll
        for (int p = 0; p < 16; ++p)
            av = fmaf(Wt[p], A[p * V + u], av);
        lds_a[u] = av;
        __syncthreads();
        const float4* a4 = (const float4*)lds_a;
        const float4* w4 = (const float4*)(W1v + (size_t)u * V);
        float acc = 0.f;
#pragma unroll
        for (int i = 0; i < V / 4; ++i) {
            float4 av2 = a4[i], wv = w4[i];
            acc += av2.x * wv.x + av2.y * wv.y + av2.z * wv.z + av2.w * wv.w;
        }
        b[u] = acc * scale;
    }
}

// ---------------- K4: main streaming kernel ----------------
// 256 threads = 4 waves; each wave handles 4 rows; grid = 4096/16 = 256 blocks (1/CU).
// LDS: M (64KB) + b (0.5KB) + rowbuf 4 waves x 4 rows x 512 f32 (32KB) = ~98.8KB.
__global__ __launch_bounds__(256) void k4_main(const float* __restrict__ feat,
                                               const float* __restrict__ times,
                                               const float* __restrict__ Mg,
                                               const float* __restrict__ bg,
                                               float* __restrict__ out) {
    __shared__ float Msh[V * V];
    __shared__ float bsh[V];
    __shared__ float rowbuf[4][4][512];

    const int tid = threadIdx.x;
    const int wave = tid >> 6;
    const int lane = tid & 63;

    // cooperative load of M: 16384 floats / 256 threads = 16 float4 each
    {
        const float4* src = (const float4*)Mg;
        float4* dst = (float4*)Msh;
#pragma unroll
        for (int i = 0; i < 16; ++i)
            dst[tid + 256 * i] = src[tid + 256 * i];
        if (tid < V) bsh[tid] = bg[tid];
    }

    // stage this wave's 4 rows (512 f32 each) into LDS, coalesced
    const int n0 = blockIdx.x * 16 + wave * 4;
#pragma unroll
    for (int r = 0; r < 4; ++r) {
        const float4* src = (const float4*)(feat + (size_t)(n0 + r) * 512);
        float4* dst = (float4*)(&rowbuf[wave][r][0]);
        dst[lane] = src[lane];
        dst[lane + 64] = src[lane + 64];
    }
    __syncthreads();

    // lane l owns output channels u = 2l and 2l+1
    float h0[4], h1[4];
    const float2 b2 = *(const float2*)&bsh[2 * lane];
#pragma unroll
    for (int r = 0; r < 4; ++r) {
        const float t = times[n0 + r];
        h0[r] = t * b2.x;
        h1[r] = t * b2.y;
    }

#pragma unroll 4
    for (int q4 = 0; q4 < V / 4; ++q4) {
        float4 f0 = *(const float4*)&rowbuf[wave][0][q4 * 4];
        float4 f1 = *(const float4*)&rowbuf[wave][1][q4 * 4];
        float4 f2 = *(const float4*)&rowbuf[wave][2][q4 * 4];
        float4 f3 = *(const float4*)&rowbuf[wave][3][q4 * 4];
        const float fm[4][4] = {{f0.x, f0.y, f0.z, f0.w},
                                {f1.x, f1.y, f1.z, f1.w},
                                {f2.x, f2.y, f2.z, f2.w},
                                {f3.x, f3.y, f3.z, f3.w}};
#pragma unroll
        for (int j = 0; j < 4; ++j) {
            const float2 m2 = *(const float2*)&Msh[(q4 * 4 + j) * V + 2 * lane];
#pragma unroll
            for (int r = 0; r < 4; ++r) {
                h0[r] = fmaf(fm[r][j], m2.x, h0[r]);
                h1[r] = fmaf(fm[r][j], m2.y, h1[r]);
            }
        }
    }

    // epilogue: out[n,m] = sum_u vraw[u,m]*h[u]; lane l contributes u=2l,2l+1
#pragma unroll
    for (int r = 0; r < 4; ++r) {
        const float* vp = &rowbuf[wave][r][FSC + 6 * lane];
        float pm0 = vp[0] * h0[r] + vp[3] * h1[r];
        float pm1 = vp[1] * h0[r] + vp[4] * h1[r];
        float pm2 = vp[2] * h0[r] + vp[5] * h1[r];
#pragma unroll
        for (int off = 1; off < 64; off <<= 1) {
            pm0 += __shfl_xor(pm0, off, 64);
            pm1 += __shfl_xor(pm1, off, 64);
            pm2 += __shfl_xor(pm2, off, 64);
        }
        if (lane == 0) {
            out[(n0 + r) * 3 + 0] = pm0;
            out[(n0 + r) * 3 + 1] = pm1;
            out[(n0 + r) * 3 + 2] = pm2;
        }
    }
}

extern "C" void kernel_launch(void* const* d_in, const int* in_sizes, int n_in,
                              void* d_out, int out_size, void* d_ws, size_t ws_size,
                              hipStream_t stream) {
    const float* feat  = (const float*)d_in[0];  // [4096, 512]
    const float* times = (const float*)d_in[1];  // [4096, 1]
    const float* Wt    = (const float*)d_in[2];  // [1,16]
    const float* W1s   = (const float*)d_in[3];  // [144,144]
    const float* W1v   = (const float*)d_in[4];  // [128,128]
    // d_in[5] = Wss  -- unused (dead path)
    const float* Wsv   = (const float*)d_in[6];  // [144,128,128]
    // d_in[7] = Wvv  -- unused (dead path)
    const float* W2    = (const float*)d_in[8];  // [128,1]

    float* ws    = (float*)d_ws;
    float* WsvW2 = ws;           // 18432 f32
    float* A     = ws + 18432;   // 18432 f32
    float* M     = ws + 36864;   // 16384 f32
    float* b     = ws + 53248;   // 128 f32   (total ~209 KB)

    k1_wsvw2<<<dim3(4608), dim3(256), 0, stream>>>(Wsv, W2, WsvW2);
    k2_A<<<dim3(144), dim3(128), 0, stream>>>(W1s, WsvW2, A);
    k3_Mb<<<dim3(129), dim3(128), 0, stream>>>(A, W1v, Wt, M, b);
    k4_main<<<dim3(256), dim3(256), 0, stream>>>(feat, times, M, b, (float*)d_out);
}

// Round 2
// 22.644 us; speedup vs baseline: 1.1652x; 1.1652x over previous
//
#include <hip/hip_runtime.h>
#include <math.h>

// MACE equivariant score head, restructured.
// Dead code: Wss (d_in[5]), Wvv (d_in[7]) — s3=silu(s2) is deleted in the reference.
// out[n,m] = sum_c vraw[n,c,m] * h[n,c]
// h[n,c]   = t[n]*b[c] + sum_q feat[n,q] * M[q,c]
// Precompute:
//   D[u,v]  = dot(Wsv[u,v,:], W2)                       (K1, reads 9.4MB)
//   F[q,v]  = sum_u W1s[16+q,u] * D[u,v]                (K23 per-block row)
//   M[q,c]  = scale * sum_v F[q,v] * W1v[c,v]           (K23 same block)
//   b[c]    = scale * sum_v (sum_u wt~[u] D[u,v]) W1v[c,v],  wt~[u]=sum_{p<16} Wt[p] W1s[p,u]
//   scale   = 1/(S*V*sqrt(V))  (all fan-in norms folded)

#define S 144
#define V 128
#define NROW 4096

// ---------------- K1: D[u*V+v] = dot(Wsv[u,v,:], W2) ----------------
__global__ __launch_bounds__(256) void k1_D(const float* __restrict__ Wsv,
                                            const float* __restrict__ W2,
                                            float* __restrict__ D) {
    const int wave = threadIdx.x >> 6;
    const int lane = threadIdx.x & 63;
    const int uv = blockIdx.x * 4 + wave;       // grid 4608 -> uv in [0,18432)
    const float2* src = (const float2*)Wsv + (size_t)uv * 64;
    const float2* w2 = (const float2*)W2;
    float2 a = src[lane];
    float2 w = w2[lane];
    float acc = a.x * w.x + a.y * w.y;
#pragma unroll
    for (int off = 1; off < 64; off <<= 1)
        acc += __shfl_xor(acc, off, 64);
    if (lane == 0) D[uv] = acc;
}

// ---------------- K23: per-block row of M (or b) ----------------
// block q in [0,129): q<128 -> M row q; q==128 -> b.
__global__ __launch_bounds__(128) void k23_Mb(const float* __restrict__ D,
                                              const float* __restrict__ W1s,
                                              const float* __restrict__ W1v,
                                              const float* __restrict__ Wt,
                                              float* __restrict__ M,
                                              float* __restrict__ b) {
    __shared__ float w1v_lds[V * 129];   // +1 pad: column reads conflict-free
    __shared__ float wrow[S];
    __shared__ float F[V];
    const int tid = threadIdx.x;
    const int q = blockIdx.x;

    // stage W1v (row-major, padded stride 129)
    for (int i = tid; i < V * V; i += 128)
        w1v_lds[(i >> 7) * 129 + (i & 127)] = W1v[i];

    if (q < V) {
        for (int u = tid; u < S; u += 128)
            wrow[u] = W1s[(16 + q) * S + u];
    } else {
        for (int u = tid; u < S; u += 128) {
            float acc = 0.f;
#pragma unroll
            for (int p = 0; p < 16; ++p)
                acc = fmaf(Wt[p], W1s[p * S + u], acc);
            wrow[u] = acc;
        }
    }
    __syncthreads();

    // F[v] = sum_u wrow[u] * D[u*V+v],  v = tid  (144 = 4*36)
    {
        float a0 = 0.f, a1 = 0.f, a2 = 0.f, a3 = 0.f;
#pragma unroll 9
        for (int u = 0; u < S; u += 4) {
            a0 = fmaf(wrow[u + 0], D[(u + 0) * V + tid], a0);
            a1 = fmaf(wrow[u + 1], D[(u + 1) * V + tid], a1);
            a2 = fmaf(wrow[u + 2], D[(u + 2) * V + tid], a2);
            a3 = fmaf(wrow[u + 3], D[(u + 3) * V + tid], a3);
        }
        F[tid] = (a0 + a1) + (a2 + a3);
    }
    __syncthreads();

    // out[c] = scale * sum_v F[v] * W1v[c,v],  c = tid
    const float scale = 1.0f / (144.0f * 128.0f * sqrtf(128.0f));
    float m0 = 0.f, m1 = 0.f;
#pragma unroll 16
    for (int v = 0; v < V; v += 2) {
        m0 = fmaf(F[v + 0], w1v_lds[tid * 129 + v + 0], m0);
        m1 = fmaf(F[v + 1], w1v_lds[tid * 129 + v + 1], m1);
    }
    const float r = (m0 + m1) * scale;
    if (q < V) M[q * V + tid] = r;
    else       b[tid] = r;
}

// ---------------- K4: main streaming kernel ----------------
// 256 blocks x 256 thr (4 waves), 16 rows/block, 4 rows/wave.
// ALL global loads issued up front (vraw->regs, scalars->LDS, M->LDS coop,
// b->regs) so HBM latency is covered even at 1 block/CU.
__global__ __launch_bounds__(256) void k4_main(const float* __restrict__ feat,
                                               const float* __restrict__ times,
                                               const float* __restrict__ Mg,
                                               const float* __restrict__ bg,
                                               float* __restrict__ out) {
    __shared__ float Msh[V * V];          // 64KB
    __shared__ float srow[4][4][V];       // 8KB
    const int tid = threadIdx.x;
    const int wave = tid >> 6;
    const int lane = tid & 63;
    const int n0 = blockIdx.x * 16 + wave * 4;

    // vector part of this wave's 4 rows -> registers (lane owns channels 2l, 2l+1)
    float2 va[4][3];
#pragma unroll
    for (int r = 0; r < 4; ++r) {
        const float* p = feat + (size_t)(n0 + r) * 512 + V + 6 * lane;
        va[r][0] = *(const float2*)(p + 0);
        va[r][1] = *(const float2*)(p + 2);
        va[r][2] = *(const float2*)(p + 4);
    }
    // scalar part of rows -> LDS (broadcast source for the GEMV)
#pragma unroll
    for (int r = 0; r < 4; ++r) {
        float2 sv = *(const float2*)(feat + (size_t)(n0 + r) * 512 + 2 * lane);
        *(float2*)&srow[wave][r][2 * lane] = sv;
    }
    // cooperative M load: 16384 f32 = 4096 float4 / 256 thr
    {
        const float4* src = (const float4*)Mg;
        float4* dst = (float4*)Msh;
#pragma unroll
        for (int i = 0; i < 16; ++i)
            dst[tid + 256 * i] = src[tid + 256 * i];
    }
    const float2 b2 = *(const float2*)(bg + 2 * lane);
    float h0[4], h1[4];
#pragma unroll
    for (int r = 0; r < 4; ++r) {
        const float t = times[n0 + r];
        h0[r] = t * b2.x;
        h1[r] = t * b2.y;
    }
    __syncthreads();

    // h[r, 2l & 2l+1] += sum_q srow[r][q] * M[q, 2l / 2l+1]
#pragma unroll 8
    for (int q = 0; q < V; ++q) {
        const float2 m2 = *(const float2*)&Msh[q * V + 2 * lane];
#pragma unroll
        for (int r = 0; r < 4; ++r) {
            const float f = srow[wave][r][q];
            h0[r] = fmaf(f, m2.x, h0[r]);
            h1[r] = fmaf(f, m2.y, h1[r]);
        }
    }

    // epilogue: out[n,m] = sum_c vraw[c,m]*h[c]; lane l holds c=2l (va[0].x,va[0].y,va[1].x)
    // and c=2l+1 (va[1].y,va[2].x,va[2].y)
#pragma unroll
    for (int r = 0; r < 4; ++r) {
        float pm0 = va[r][0].x * h0[r] + va[r][1].y * h1[r];
        float pm1 = va[r][0].y * h0[r] + va[r][2].x * h1[r];
        float pm2 = va[r][1].x * h0[r] + va[r][2].y * h1[r];
#pragma unroll
        for (int off = 1; off < 64; off <<= 1) {
            pm0 += __shfl_xor(pm0, off, 64);
            pm1 += __shfl_xor(pm1, off, 64);
            pm2 += __shfl_xor(pm2, off, 64);
        }
        if (lane == 0) {
            out[(n0 + r) * 3 + 0] = pm0;
            out[(n0 + r) * 3 + 1] = pm1;
            out[(n0 + r) * 3 + 2] = pm2;
        }
    }
}

extern "C" void kernel_launch(void* const* d_in, const int* in_sizes, int n_in,
                              void* d_out, int out_size, void* d_ws, size_t ws_size,
                              hipStream_t stream) {
    const float* feat  = (const float*)d_in[0];  // [4096, 512]
    const float* times = (const float*)d_in[1];  // [4096, 1]
    const float* Wt    = (const float*)d_in[2];  // [1,16]
    const float* W1s   = (const float*)d_in[3];  // [144,144]
    const float* W1v   = (const float*)d_in[4];  // [128,128]
    // d_in[5] = Wss  -- dead path
    const float* Wsv   = (const float*)d_in[6];  // [144,128,128]
    // d_in[7] = Wvv  -- dead path
    const float* W2    = (const float*)d_in[8];  // [128,1]

    float* ws = (float*)d_ws;
    float* D  = ws;            // 18432 f32
    float* M  = ws + 18432;    // 16384 f32
    float* b  = ws + 34816;    // 128 f32

    k1_D<<<dim3(4608), dim3(256), 0, stream>>>(Wsv, W2, D);
    k23_Mb<<<dim3(129), dim3(128), 0, stream>>>(D, W1s, W1v, Wt, M, b);
    k4_main<<<dim3(256), dim3(256), 0, stream>>>(feat, times, M, b, (float*)d_out);
}